// Round 12
// baseline (248.848 us; speedup 1.0000x reference)
//
#include <hip/hip_runtime.h>
#include <hip/hip_bf16.h>

#define B_SZ 8
#define N_Q 512
#define M_KV 4096
#define DIM 1024
#define INNER 512
#define NHEADS 8
#define HDIM 64

typedef __attribute__((ext_vector_type(4))) float floatx4;
typedef __attribute__((ext_vector_type(8))) short shortx8;
typedef __attribute__((ext_vector_type(4))) short shortx4;

#define QSCALE 0.18033688011112042f  /* 0.125 * log2(e): attn uses exp2 */

__device__ inline unsigned short f2bf(float f) {
  union { float f; unsigned u; } x; x.f = f;
  unsigned r = x.u + 0x7FFFu + ((x.u >> 16) & 1u);
  return (unsigned short)(r >> 16);
}

__device__ inline shortx8 cvt8(floatx4 a, floatx4 b) {
  shortx8 h;
  h[0] = (short)f2bf(a[0]); h[1] = (short)f2bf(a[1]);
  h[2] = (short)f2bf(a[2]); h[3] = (short)f2bf(a[3]);
  h[4] = (short)f2bf(b[0]); h[5] = (short)f2bf(b[1]);
  h[6] = (short)f2bf(b[2]); h[7] = (short)f2bf(b[3]);
  return h;
}

__device__ inline void gload16(const void* g, void* l) {
  __builtin_amdgcn_global_load_lds(
      (const __attribute__((address_space(1))) void*)g,
      (__attribute__((address_space(3))) void*)l, 16, 0, 0);
}

// fp32 -> bf16 bulk convert (memory-bound, grid-stride)
__global__ void k_cvt_bf16(const float* __restrict__ src,
                           unsigned short* __restrict__ dst, long n) {
  long stride = (long)gridDim.x * 256 * 8;
  for (long i = ((long)blockIdx.x * 256 + threadIdx.x) * 8; i < n; i += stride) {
    floatx4 a = *reinterpret_cast<const floatx4*>(src + i);
    floatx4 b = *reinterpret_cast<const floatx4*>(src + i + 4);
    *reinterpret_cast<shortx8*>(dst + i) = cvt8(a, b);
  }
}

// All four weight transposes in ONE launch. z=0:Wq z=1:Wk z=2:Wv z=3:Wo.
__global__ void k_transpose_all(const float* __restrict__ Wq,
                                const float* __restrict__ Wk,
                                const float* __restrict__ Wv,
                                const float* __restrict__ Wo,
                                unsigned short* __restrict__ Wqt,
                                unsigned short* __restrict__ Wkvt,
                                unsigned short* __restrict__ Wot) {
  __shared__ unsigned short t[32][36];
  const int z = blockIdx.z;
  const float* W;
  unsigned short* Wt;
  int K, N;
  if (z == 0)      { W = Wq; Wt = Wqt;  K = 1024; N = 512; }
  else if (z == 1) { W = Wk; Wt = Wkvt; K = 1024; N = 512; }
  else if (z == 2) { W = Wv; Wt = Wkvt + (size_t)512 * 1024; K = 1024; N = 512; }
  else             { W = Wo; Wt = Wot;  K = 512;  N = 1024; }
  if ((int)blockIdx.x * 32 >= K || (int)blockIdx.y * 32 >= N) return;
  const int kt = blockIdx.x * 32, nt = blockIdx.y * 32;
  const int tr = threadIdx.x >> 3;
  const int tc = (threadIdx.x & 7) * 4;
  floatx4 v = *reinterpret_cast<const floatx4*>(&W[(long)(kt + tr) * N + nt + tc]);
  #pragma unroll
  for (int j = 0; j < 4; ++j) t[tr][tc + j] = f2bf(v[j]);
  __syncthreads();
  shortx4 o;
  #pragma unroll
  for (int j = 0; j < 4; ++j) o[j] = (short)t[tc + j][tr];
  *reinterpret_cast<shortx4*>(&Wt[(long)(nt + tr) * K + kt + tc]) = o;
}

// Fused K+V projection (R8/R10 proven): 128x128 tile, BK=32, 4 waves,
// A and B via global_load_lds w=16 (swizzled global src, linear LDS dest),
// dbuf, ONE __syncthreads per K-step, setprio on MFMA. 4 blocks/CU.
__global__ __launch_bounds__(256, 4)
void k_gemm_kv(const unsigned short* __restrict__ Ah,
               const unsigned short* __restrict__ Wkvt,
               unsigned short* __restrict__ Kh,
               unsigned short* __restrict__ Vt) {
  __shared__ unsigned short As[2][128 * 32];
  __shared__ unsigned short Bs[2][128 * 32];
  const int tid = threadIdx.x;
  const int lane = tid & 63;
  const int w = tid >> 6;
  const int wr = w >> 1, wc = w & 1;
  const int fr = lane & 15, fc = lane >> 4;

  const int L = ((blockIdx.x & 7) << 8) + (blockIdx.x >> 3);
  const int mt = L >> 3, nt = L & 7;
  const long arow0 = (long)mt << 7;
  const long bcol0 = (long)nt << 7;

  const int grow = lane >> 2;
  const int gpos = lane & 3;

  floatx4 acc[4][4] = {};

  #define STAGE(buf, kt)                                                      \
    {                                                                         \
      _Pragma("unroll")                                                       \
      for (int g = 0; g < 2; ++g) {                                           \
        const int rl = w * 32 + g * 16 + grow;                                \
        const int cc = gpos ^ ((rl >> 1) & 3);                                \
        gload16(Ah + (arow0 + rl) * 1024 + (kt) + cc * 8,                     \
                &As[buf][(w * 32 + g * 16) * 32]);                            \
        gload16(Wkvt + (bcol0 + rl) * 1024 + (kt) + cc * 8,                   \
                &Bs[buf][(w * 32 + g * 16) * 32]);                            \
      }                                                                       \
    }

  STAGE(0, 0);
  __syncthreads();

  for (int i = 0; i < 32; ++i) {
    const int cur = i & 1;
    if (i < 31) STAGE(cur ^ 1, (i + 1) << 5);

    shortx8 af[4], bf[4];
    #pragma unroll
    for (int rb = 0; rb < 4; ++rb) {
      int row = wr * 64 + rb * 16 + fr;
      af[rb] = *reinterpret_cast<const shortx8*>(
          &As[cur][row * 32 + ((fc ^ ((row >> 1) & 3)) * 8)]);
    }
    #pragma unroll
    for (int cb = 0; cb < 4; ++cb) {
      int row = wc * 64 + cb * 16 + fr;
      bf[cb] = *reinterpret_cast<const shortx8*>(
          &Bs[cur][row * 32 + ((fc ^ ((row >> 1) & 3)) * 8)]);
    }
    __builtin_amdgcn_s_setprio(1);
    #pragma unroll
    for (int rb = 0; rb < 4; ++rb) {
      #pragma unroll
      for (int cb = 0; cb < 4; ++cb)
        acc[rb][cb] = __builtin_amdgcn_mfma_f32_16x16x32_bf16(
            af[rb], bf[cb], acc[rb][cb], 0, 0, 0);
    }
    __builtin_amdgcn_s_setprio(0);
    __syncthreads();
  }
  #undef STAGE

  #pragma unroll
  for (int rb = 0; rb < 4; ++rb) {
    #pragma unroll
    for (int cb = 0; cb < 4; ++cb) {
      long gr0 = arow0 + wr * 64 + rb * 16 + fc * 4;
      long gc = bcol0 + wc * 64 + cb * 16 + fr;
      long b = gr0 >> 12, m = gr0 & 4095;
      if (gc < 512) {
        long h = gc >> 6, d = gc & 63;
        #pragma unroll
        for (int r = 0; r < 4; ++r)
          Kh[((((b * 8 + h) << 12) + m + r) << 6) + d] = f2bf(acc[rb][cb][r]);
      } else {
        long h = (gc - 512) >> 6, d = (gc - 512) & 63;
        shortx4 hv;
        #pragma unroll
        for (int r = 0; r < 4; ++r) hv[r] = (short)f2bf(acc[rb][cb][r]);
        *reinterpret_cast<shortx4*>(&Vt[(((b * 8 + h) * 64 + d) << 12) + m]) = hv;
      }
    }
  }
}

// Q projection: 128x128 tile, A = x fp32 reg-staged (cvt inline), B = Wqt
// via gload. Output head-blocked [b][h][n][d], scale folded (exp2). 128 blk.
__global__ __launch_bounds__(256, 4)
void k_qproj(const float* __restrict__ x,
             const unsigned short* __restrict__ Wqt,
             unsigned short* __restrict__ Qh) {
  __shared__ unsigned short As[2][4096];
  __shared__ unsigned short Bs[2][4096];
  const int tid = threadIdx.x;
  const int lane = tid & 63;
  const int w = tid >> 6;
  const int wr = w >> 1, wc = w & 1;
  const int fr = lane & 15, fc = lane >> 4;

  const int L = ((blockIdx.x & 7) << 4) + (blockIdx.x >> 3);
  const long arow0 = (long)(L >> 2) << 7;
  const long bcol0 = (long)(L & 3) << 7;

  const int grow = lane >> 2;
  const int gpos = lane & 3;
  const int arw = tid >> 1;
  const int ahalf = tid & 1;
  const int aswz = (arw >> 1) & 3;
  const int as0 = ((2 * ahalf) ^ aswz) * 8;
  const int as1 = ((2 * ahalf + 1) ^ aswz) * 8;

  floatx4 acc[4][4] = {};

  #define STAGE_B(buf, kt)                                                    \
    { _Pragma("unroll")                                                       \
      for (int g = 0; g < 2; ++g) {                                           \
        const int rl = w * 32 + g * 16 + grow;                                \
        const int cc = gpos ^ ((rl >> 1) & 3);                                \
        gload16(Wqt + (bcol0 + rl) * 1024 + (kt) + cc * 8,                    \
                &Bs[buf][(w * 32 + g * 16) * 32]);                            \
      } }

  {
    const float* s = x + (arow0 + arw) * 1024 + ahalf * 16;
    floatx4 a0 = *reinterpret_cast<const floatx4*>(s);
    floatx4 a1 = *reinterpret_cast<const floatx4*>(s + 4);
    floatx4 a2 = *reinterpret_cast<const floatx4*>(s + 8);
    floatx4 a3 = *reinterpret_cast<const floatx4*>(s + 12);
    STAGE_B(0, 0);
    *reinterpret_cast<shortx8*>(&As[0][arw * 32 + as0]) = cvt8(a0, a1);
    *reinterpret_cast<shortx8*>(&As[0][arw * 32 + as1]) = cvt8(a2, a3);
  }
  __syncthreads();

  for (int i = 0; i < 32; ++i) {
    const int cur = i & 1;
    const bool more = i < 31;
    floatx4 a0, a1, a2, a3;
    if (more) {
      const int ktn = (i + 1) << 5;
      const float* s = x + (arow0 + arw) * 1024 + ktn + ahalf * 16;
      a0 = *reinterpret_cast<const floatx4*>(s);
      a1 = *reinterpret_cast<const floatx4*>(s + 4);
      a2 = *reinterpret_cast<const floatx4*>(s + 8);
      a3 = *reinterpret_cast<const floatx4*>(s + 12);
      STAGE_B(cur ^ 1, ktn);
    }

    shortx8 af[4], bf[4];
    #pragma unroll
    for (int rb = 0; rb < 4; ++rb) {
      int row = wr * 64 + rb * 16 + fr;
      af[rb] = *reinterpret_cast<const shortx8*>(
          &As[cur][row * 32 + ((fc ^ ((row >> 1) & 3)) * 8)]);
    }
    #pragma unroll
    for (int cb = 0; cb < 4; ++cb) {
      int row = wc * 64 + cb * 16 + fr;
      bf[cb] = *reinterpret_cast<const shortx8*>(
          &Bs[cur][row * 32 + ((fc ^ ((row >> 1) & 3)) * 8)]);
    }
    __builtin_amdgcn_s_setprio(1);
    #pragma unroll
    for (int rb = 0; rb < 4; ++rb) {
      #pragma unroll
      for (int cb = 0; cb < 4; ++cb)
        acc[rb][cb] = __builtin_amdgcn_mfma_f32_16x16x32_bf16(
            af[rb], bf[cb], acc[rb][cb], 0, 0, 0);
    }
    __builtin_amdgcn_s_setprio(0);

    if (more) {
      *reinterpret_cast<shortx8*>(&As[cur ^ 1][arw * 32 + as0]) = cvt8(a0, a1);
      *reinterpret_cast<shortx8*>(&As[cur ^ 1][arw * 32 + as1]) = cvt8(a2, a3);
    }
    __syncthreads();
  }
  #undef STAGE_B

  #pragma unroll
  for (int rb = 0; rb < 4; ++rb) {
    #pragma unroll
    for (int cb = 0; cb < 4; ++cb) {
      long gr0 = arow0 + wr * 64 + rb * 16 + fc * 4;
      long gc = bcol0 + wc * 64 + cb * 16 + fr;
      long b = gr0 >> 9, m = gr0 & 511;
      long h = gc >> 6, d = gc & 63;
      #pragma unroll
      for (int r = 0; r < 4; ++r)
        Qh[((((b * 8 + h) << 9) + m + r) << 6) + d] =
            f2bf(acc[rb][cb][r] * QSCALE);
    }
  }
}

// Output projection (proven body): A=Aat bf16 via gload, B=Wot, K=512,
// fp32 out + bias. 256 blocks, 4/CU.
__global__ __launch_bounds__(256, 4)
void k_out(const unsigned short* __restrict__ Aat,
           const unsigned short* __restrict__ Wot,
           float* __restrict__ out, const float* __restrict__ bias) {
  __shared__ unsigned short As[2][4096];
  __shared__ unsigned short Bs[2][4096];
  const int tid = threadIdx.x;
  const int lane = tid & 63;
  const int w = tid >> 6;
  const int wr = w >> 1, wc = w & 1;
  const int fr = lane & 15, fc = lane >> 4;

  const int L = ((blockIdx.x & 7) << 5) + (blockIdx.x >> 3);
  const long arow0 = (long)(L >> 3) << 7;
  const long bcol0 = (long)(L & 7) << 7;

  const int grow = lane >> 2;
  const int gpos = lane & 3;

  floatx4 acc[4][4] = {};

  #define STAGE2(buf, kt)                                                     \
    { _Pragma("unroll")                                                       \
      for (int g = 0; g < 2; ++g) {                                           \
        const int rl = w * 32 + g * 16 + grow;                                \
        const int cc = gpos ^ ((rl >> 1) & 3);                                \
        gload16(Aat + (arow0 + rl) * 512 + (kt) + cc * 8,                     \
                &As[buf][(w * 32 + g * 16) * 32]);                            \
        gload16(Wot + (bcol0 + rl) * 512 + (kt) + cc * 8,                     \
                &Bs[buf][(w * 32 + g * 16) * 32]);                            \
      } }

  STAGE2(0, 0);
  __syncthreads();

  for (int i = 0; i < 16; ++i) {
    const int cur = i & 1;
    if (i < 15) STAGE2(cur ^ 1, (i + 1) << 5);

    shortx8 af[4], bf[4];
    #pragma unroll
    for (int rb = 0; rb < 4; ++rb) {
      int row = wr * 64 + rb * 16 + fr;
      af[rb] = *reinterpret_cast<const shortx8*>(
          &As[cur][row * 32 + ((fc ^ ((row >> 1) & 3)) * 8)]);
    }
    #pragma unroll
    for (int cb = 0; cb < 4; ++cb) {
      int row = wc * 64 + cb * 16 + fr;
      bf[cb] = *reinterpret_cast<const shortx8*>(
          &Bs[cur][row * 32 + ((fc ^ ((row >> 1) & 3)) * 8)]);
    }
    __builtin_amdgcn_s_setprio(1);
    #pragma unroll
    for (int rb = 0; rb < 4; ++rb) {
      #pragma unroll
      for (int cb = 0; cb < 4; ++cb)
        acc[rb][cb] = __builtin_amdgcn_mfma_f32_16x16x32_bf16(
            af[rb], bf[cb], acc[rb][cb], 0, 0, 0);
    }
    __builtin_amdgcn_s_setprio(0);
    __syncthreads();
  }
  #undef STAGE2

  #pragma unroll
  for (int rb = 0; rb < 4; ++rb) {
    #pragma unroll
    for (int cb = 0; cb < 4; ++cb) {
      long gr0 = arow0 + wr * 64 + rb * 16 + fc * 4;
      long gc = bcol0 + wc * 64 + cb * 16 + fr;
      float bv = bias[gc];
      #pragma unroll
      for (int r = 0; r < 4; ++r)
        out[(gr0 + r) * 1024 + gc] = acc[rb][cb][r] + bv;
    }
  }
}

// Flash attention with SWAPPED QK^T (mfma(K,Q) -> S^T): P lands with 4
// consecutive m per lane, so P->LDS is 8 ds_write_b64 instead of 32 b16.
// Wave-tile 32x64, sp=4 KV-splits, gload-staged dbuf K/V, exp2.
__global__ __launch_bounds__(256, 3)
void k_attn(const unsigned short* __restrict__ Qh,
            const unsigned short* __restrict__ Kh,
            const unsigned short* __restrict__ Vt,
            float* __restrict__ Opart, float* __restrict__ Lpart) {
  __shared__ unsigned short Ks[2][64 * 64];
  __shared__ unsigned short Vs[2][64 * 64];
  __shared__ unsigned short QPs[128 * 72];  // Q staged linear [128*64]; P as [128][72]
  const int tid = threadIdx.x;
  const int lane = tid & 63;
  const int w = tid >> 6;
  const int wg = blockIdx.x;          // (sp*4 + qt)*64 + bh
  const int bh = wg & 63;             // XCD = bh%8 -> K/V L2 shared
  const int qt = (wg >> 6) & 3;
  const int sp = wg >> 8;
  const int fr = lane & 15, fc = lane >> 4;

  const unsigned short* Qbase = Qh + (((long)bh << 9) + qt * 128) * 64;
  const unsigned short* Kbase = Kh + (((long)bh) << 18);
  const unsigned short* Vbase = Vt + (((long)bh) << 18);

  const int grow = lane >> 3;   // 0..7
  const int gpos = lane & 7;    // 16B slot in 128B row

  #define STAGE_KV(buf, mt_)                                              \
    { _Pragma("unroll")                                                   \
      for (int j = 0; j < 2; ++j) {                                       \
        const int r = w * 16 + j * 8 + grow;                              \
        const int c = gpos ^ (r & 7);                                     \
        gload16(Kbase + ((mt_) * 64 + r) * 64 + c * 8,                    \
                &Ks[buf][(w * 16 + j * 8) * 64]);                         \
        gload16(Vbase + (((long)r) << 12) + (mt_) * 64 + c * 8,           \
                &Vs[buf][(w * 16 + j * 8) * 64]);                         \
      } }

  const int mt0 = sp * 16;
  {
    #pragma unroll
    for (int j = 0; j < 4; ++j) {
      const int r = w * 32 + j * 8 + grow;
      const int c = gpos ^ (r & 7);
      gload16(Qbase + r * 64 + c * 8, &QPs[(w * 32 + j * 8) * 64]);
    }
    STAGE_KV(0, mt0);
  }
  __syncthreads();

  shortx8 qf[2][2];
  #pragma unroll
  for (int qb = 0; qb < 2; ++qb) {
    const int row = w * 32 + qb * 16 + fr;
    #pragma unroll
    for (int kk = 0; kk < 2; ++kk)
      qf[qb][kk] = *reinterpret_cast<const shortx8*>(
          &QPs[row * 64 + (((kk * 4 + fc) ^ (row & 7)) * 8)]);
  }
  __syncthreads();  // all Q reads done before P overwrites the buffer

  floatx4 o_acc[2][4] = {};
  float lql[2] = {0.f, 0.f};  // per-lane l for q = w*32 + qb*16 + fr

  for (int it = 0; it < 16; ++it) {
    const int cur = it & 1;
    if (it < 15) STAGE_KV(cur ^ 1, mt0 + it + 1);

    // S^T = K Q^T : s[qb][mb], lane holds q=fr, m=mb*16+fc*4+r
    floatx4 s[2][4];
    __builtin_amdgcn_s_setprio(1);
    #pragma unroll
    for (int mb = 0; mb < 4; ++mb) {
      const int krow = mb * 16 + fr;
      shortx8 k0 = *reinterpret_cast<const shortx8*>(
          &Ks[cur][krow * 64 + ((fc ^ (fr & 7)) * 8)]);
      shortx8 k1 = *reinterpret_cast<const shortx8*>(
          &Ks[cur][krow * 64 + (((4 + fc) ^ (fr & 7)) * 8)]);
      #pragma unroll
      for (int qb = 0; qb < 2; ++qb) {
        floatx4 z = {};
        z = __builtin_amdgcn_mfma_f32_16x16x32_bf16(k0, qf[qb][0], z, 0, 0, 0);
        s[qb][mb] = __builtin_amdgcn_mfma_f32_16x16x32_bf16(
            k1, qf[qb][1], z, 0, 0, 0);
      }
    }
    __builtin_amdgcn_s_setprio(0);

    // exp2, pack 4 consecutive m -> one b64 write; accumulate per-lane l
    #pragma unroll
    for (int qb = 0; qb < 2; ++qb) {
      #pragma unroll
      for (int mb = 0; mb < 4; ++mb) {
        shortx4 pk;
        #pragma unroll
        for (int r = 0; r < 4; ++r) {
          float pv = exp2f(s[qb][mb][r]);
          lql[qb] += pv;
          pk[r] = (short)f2bf(pv);
        }
        *reinterpret_cast<shortx4*>(
            &QPs[(w * 32 + qb * 16 + fr) * 72 + mb * 16 + fc * 4]) = pk;
      }
    }

    // O += P V (A=P rows q, B=V^T cols d) — unchanged
    __builtin_amdgcn_s_setprio(1);
    #pragma unroll
    for (int kk = 0; kk < 2; ++kk) {
      shortx8 pf[2];
      #pragma unroll
      for (int qb = 0; qb < 2; ++qb)
        pf[qb] = *reinterpret_cast<const shortx8*>(
            &QPs[(w * 32 + qb * 16 + fr) * 72 + kk * 32 + fc * 8]);
      #pragma unroll
      for (int db = 0; db < 4; ++db) {
        const int vrow = db * 16 + fr;
        shortx8 vf = *reinterpret_cast<const shortx8*>(
            &Vs[cur][vrow * 64 + (((kk * 4 + fc) ^ (fr & 7)) * 8)]);
        #pragma unroll
        for (int qb = 0; qb < 2; ++qb)
          o_acc[qb][db] = __builtin_amdgcn_mfma_f32_16x16x32_bf16(
              pf[qb], vf, o_acc[qb][db], 0, 0, 0);
      }
    }
    __builtin_amdgcn_s_setprio(0);
    __syncthreads();
  }
  #undef STAGE_KV

  // l: reduce across the 4 fc-lane groups (lane bits 4,5)
  #pragma unroll
  for (int qb = 0; qb < 2; ++qb) {
    float l = lql[qb];
    l += __shfl_xor(l, 16);
    l += __shfl_xor(l, 32);
    if (fc == 0) Lpart[(long)wg * 128 + w * 32 + qb * 16 + fr] = l;
  }
  float* Ob = Opart + (long)wg * 8192;
  #pragma unroll
  for (int qb = 0; qb < 2; ++qb) {
    #pragma unroll
    for (int r = 0; r < 4; ++r) {
      const int prow = w * 32 + qb * 16 + fc * 4 + r;
      #pragma unroll
      for (int db = 0; db < 4; ++db)
        Ob[prow * 64 + db * 16 + fr] = o_acc[qb][db][r];
    }
  }
}

// Combine 4 KV-splits: Aat[b][n][h*64+d] = sum(O_p)/sum(l_p), bf16.
__global__ void k_attn_reduce(const float* __restrict__ Opart,
                              const float* __restrict__ Lpart,
                              unsigned short* __restrict__ Aat) {
  const int tid = threadIdx.x;
  const int g = blockIdx.x * 4 + (tid >> 6);  // row, 0..32767
  const int d = tid & 63;
  const int bh = g >> 9, n = g & 511;
  const int b = bh >> 3, h = bh & 7;
  const int qt = n >> 7, rr = n & 127;
  float o = 0.f, l = 0.f;
  #pragma unroll
  for (int p = 0; p < 4; ++p) {
    const long wgp = ((p * 4 + qt) << 6) + bh;
    o += Opart[wgp * 8192 + rr * 64 + d];
    l += Lpart[wgp * 128 + rr];
  }
  Aat[((long)(b * 512 + n)) * 512 + h * 64 + d] = f2bf(o / l);
}

extern "C" void kernel_launch(void* const* d_in, const int* in_sizes, int n_in,
                              void* d_out, int out_size, void* d_ws, size_t ws_size,
                              hipStream_t stream) {
  const float* x   = (const float*)d_in[0];
  const float* ctx = (const float*)d_in[1];
  const float* Wq  = (const float*)d_in[2];
  const float* Wk  = (const float*)d_in[3];
  const float* Wv  = (const float*)d_in[4];
  const float* Wo  = (const float*)d_in[5];
  const float* bo  = (const float*)d_in[6];
  float* out = (float*)d_out;

  char* ws = (char*)d_ws;
  unsigned short* Qh   = (unsigned short*)(ws);                    // 4MB
  unsigned short* Kh   = (unsigned short*)(ws + (4ull  << 20));    // 32MB
  unsigned short* Vt   = (unsigned short*)(ws + (36ull << 20));    // 32MB
  unsigned short* ctxh = (unsigned short*)(ws + (68ull << 20));    // 64MB
  unsigned short* Aat  = (unsigned short*)(ws + (68ull << 20));    // 4MB, aliases ctxh (dead after KV)
  float*          Opart= (float*)         (ws + (76ull << 20));    // 32MB, inside dead ctxh
  float*          Lpart= (float*)         (ws + (110ull << 20));   // 512KB
  unsigned short* Wqt  = (unsigned short*)(ws + (132ull << 20));   // 1MB
  unsigned short* Wkvt = (unsigned short*)(ws + (133ull << 20));   // 2MB
  unsigned short* Wot  = (unsigned short*)(ws + (135ull << 20));   // 1MB

  k_cvt_bf16<<<dim3(2048), dim3(256), 0, stream>>>(
      ctx, ctxh, (long)B_SZ * M_KV * DIM);

  k_transpose_all<<<dim3(32, 32, 4), dim3(256), 0, stream>>>(
      Wq, Wk, Wv, Wo, Wqt, Wkvt, Wot);

  // Q projection (128 blocks) and fused K+V projection (2048 blocks, proven)
  k_qproj<<<dim3(128), dim3(256), 0, stream>>>(x, Wqt, Qh);
  k_gemm_kv<<<dim3(2048), dim3(256), 0, stream>>>(ctxh, Wkvt, Kh, Vt);

  // attention: 1024 blocks (4 KV-splits x 4 q-tiles x 64 bh), then combine
  k_attn<<<dim3(1024), dim3(256), 0, stream>>>(Qh, Kh, Vt, Opart, Lpart);
  k_attn_reduce<<<dim3(8192), dim3(256), 0, stream>>>(Opart, Lpart, Aat);

  // output projection + bias, fp32 out
  k_out<<<dim3(256), dim3(256), 0, stream>>>(Aat, Wot, out, bo);
}